// Round 5
// baseline (290.752 us; speedup 1.0000x reference)
//
#include <hip/hip_runtime.h>

#define S_LEN 2048
#define DIM   1024
#define NH    16
#define HD    64

typedef __bf16 bf16x8 __attribute__((ext_vector_type(8)));
typedef __bf16 bf16x4 __attribute__((ext_vector_type(4)));
typedef float  f32x4  __attribute__((ext_vector_type(4)));

// softmax scale 1/8 with log2(e) folded in -> use v_exp_f32 (exp2) directly
#define SCALE_Q (0.125f * 1.44269504088896f)

#define GLOAD_LDS16(g, l) __builtin_amdgcn_global_load_lds( \
    (const __attribute__((address_space(1))) void*)(g),     \
    (__attribute__((address_space(3))) void*)(l), 16, 0, 0)

// ---------------- cast x (fp32 -> bf16), 8 elems/thread ----------------
__global__ __launch_bounds__(256) void cast_x_kernel(const float* __restrict__ x,
                                                     __bf16* __restrict__ xb) {
  int i = blockIdx.x * 256 + threadIdx.x;   // 0..524287
  const float4 a = ((const float4*)x)[i * 2];
  const float4 b = ((const float4*)x)[i * 2 + 1];
  bf16x8 o;
  o[0] = (__bf16)a.x; o[1] = (__bf16)a.y; o[2] = (__bf16)a.z; o[3] = (__bf16)a.w;
  o[4] = (__bf16)b.x; o[5] = (__bf16)b.y; o[6] = (__bf16)b.z; o[7] = (__bf16)b.w;
  ((bf16x8*)xb)[i] = o;
}

// ---------------- W [k][n] fp32 -> WT [n][k] bf16, 64x64 LDS tiles ----------------
__global__ __launch_bounds__(256) void transW_kernel(const float* __restrict__ Wq,
                                                     const float* __restrict__ Wk,
                                                     const float* __restrict__ Wv,
                                                     __bf16* __restrict__ WT) {
  int which = blockIdx.z;
  const float* W = (which == 0) ? Wq : ((which == 1) ? Wk : Wv);
  __bf16* o = WT + (size_t)which * DIM * DIM;
  __shared__ __bf16 t[64][65];
  int k0 = blockIdx.y * 64, n0 = blockIdx.x * 64;
  int tid = threadIdx.x;
  int c4 = (tid & 15) * 4, rb = tid >> 4;   // rb 0..15
#pragma unroll
  for (int p = 0; p < 4; ++p) {
    int r = p * 16 + rb;
    float4 a = *(const float4*)&W[(size_t)(k0 + r) * DIM + n0 + c4];
    t[r][c4 + 0] = (__bf16)a.x; t[r][c4 + 1] = (__bf16)a.y;
    t[r][c4 + 2] = (__bf16)a.z; t[r][c4 + 3] = (__bf16)a.w;
  }
  __syncthreads();
#pragma unroll
  for (int p = 0; p < 4; ++p) {
    int n = p * 16 + rb;                     // output row (n dim)
    bf16x4 v;
    v[0] = t[c4 + 0][n]; v[1] = t[c4 + 1][n];
    v[2] = t[c4 + 2][n]; v[3] = t[c4 + 3][n];
    *(bf16x4*)&o[(size_t)(n0 + n) * DIM + k0 + c4] = v;
  }
}

// ---------------- QKV GEMM, m97 structure: global_load_lds staging, linear LDS ----------------
// which==0 (Q): output pre-scaled by SCALE_Q (softmax+log2e folded).
// which==1 (K): [b,h,s,hd].  which==2 (V): TRANSPOSED [b,h,hd,s] via LDS tile transpose.
__global__ __launch_bounds__(256) void qkv_gemm_kernel(const __bf16* __restrict__ xb,
                                                       const __bf16* __restrict__ WT,
                                                       const float* __restrict__ bq,
                                                       const float* __restrict__ bk,
                                                       const float* __restrict__ bv,
                                                       __bf16* __restrict__ qkv) {
  int which = blockIdx.z;
  const __bf16* Wt = WT + (size_t)which * DIM * DIM;
  const float* bias = (which == 0) ? bq : ((which == 1) ? bk : bv);
  __bf16* outp = qkv + (size_t)which * 2 * NH * S_LEN * HD;
  int m0 = blockIdx.y * 128;
  int n0 = blockIdx.x * 128;
  __shared__ __align__(16) char smem[36864];
  __bf16 (*As)[64] = (__bf16(*)[64])smem;            // 16384 B, linear (for global_load_lds)
  __bf16 (*Bs)[64] = (__bf16(*)[64])(smem + 16384);  // 16384 B
  __bf16 (*Ct)[136] = (__bf16(*)[136])smem;          // aliased; used only after final barrier
  int tid = threadIdx.x;
  int wave = tid >> 6, lane = tid & 63;
  int g = lane >> 4, l15 = lane & 15;
  int wm = (wave >> 1) * 64, wn = (wave & 1) * 64;
  // staging: wave w owns rows w*32..w*32+31; each GLL writes 1KB = 8 rows x 128B
  int lr = lane >> 3;            // 0..7 row within 8-row chunk
  int lc = (lane & 7) * 8;       // elem col (16B per lane)
  const __bf16* ga = &xb[(size_t)(m0 + wave * 32 + lr) * DIM + lc];
  const __bf16* gb = &Wt[(size_t)(n0 + wave * 32 + lr) * DIM + lc];
  f32x4 acc[4][4] = {};
  for (int k0 = 0; k0 < DIM; k0 += 64) {
#pragma unroll
    for (int c = 0; c < 4; ++c) {
      GLOAD_LDS16(ga + k0 + (size_t)(c * 8) * DIM, &As[wave * 32 + c * 8][0]);
      GLOAD_LDS16(gb + k0 + (size_t)(c * 8) * DIM, &Bs[wave * 32 + c * 8][0]);
    }
    __syncthreads();
#pragma unroll
    for (int ks = 0; ks < 2; ++ks) {
      bf16x8 af[4], bfr[4];
#pragma unroll
      for (int s = 0; s < 4; ++s) {
        af[s]  = *(const bf16x8*)&As[wm + s * 16 + l15][ks * 32 + g * 8];
        bfr[s] = *(const bf16x8*)&Bs[wn + s * 16 + l15][ks * 32 + g * 8];
      }
#pragma unroll
      for (int i = 0; i < 4; ++i)
#pragma unroll
        for (int j = 0; j < 4; ++j)
          acc[i][j] = __builtin_amdgcn_mfma_f32_16x16x32_bf16(af[i], bfr[j], acc[i][j], 0, 0, 0);
    }
    __syncthreads();
  }
  if (which != 2) {
    float scale = (which == 0) ? SCALE_Q : 1.0f;
#pragma unroll
    for (int i = 0; i < 4; ++i)
#pragma unroll
      for (int j = 0; j < 4; ++j) {
        int n = n0 + wn + j * 16 + l15;
        float bval = bias[n];
#pragma unroll
        for (int r = 0; r < 4; ++r) {
          int m = m0 + wm + i * 16 + g * 4 + r;
          float val = (acc[i][j][r] + bval) * scale;
          int bb = m >> 11, ss = m & 2047;
          int hh = n >> 6, hd = n & 63;
          outp[(((size_t)bb * NH + hh) * S_LEN + ss) * HD + hd] = (__bf16)val;
        }
      }
  } else {
    // V: transpose tile in LDS (writes are bf16x4 along contiguous m), store [b,h,hd,s]
#pragma unroll
    for (int i = 0; i < 4; ++i)
#pragma unroll
      for (int j = 0; j < 4; ++j) {
        int nl = wn + j * 16 + l15;
        float bval = bias[n0 + nl];
        bf16x4 t;
#pragma unroll
        for (int r = 0; r < 4; ++r) t[r] = (__bf16)(acc[i][j][r] + bval);
        *(bf16x4*)&Ct[nl][wm + i * 16 + g * 4] = t;
      }
    __syncthreads();
#pragma unroll
    for (int it = 0; it < 8; ++it) {
      int idx = (it * 256 + tid) * 8;
      int row = idx >> 7, col = idx & 127;       // row = n_local, col = m_local
      int n = n0 + row, hh = n >> 6, hd = n & 63;
      int m = m0 + col, bb = m >> 11, ss = m & 2047;
      *(bf16x8*)&outp[(((size_t)bb * NH + hh) * HD + hd) * S_LEN + ss] =
          *(const bf16x8*)&Ct[row][col];
    }
  }
}

// ---------------- flash attention + residual, QBLK=128 ----------------
// Q pre-scaled by SCALE_Q (exp2 domain); V pre-transposed [b,h,hd,s].
// Each wave owns TWO 16-q groups so the kf/vf LDS reads amortize over 2x MFMA.
__global__ __launch_bounds__(256) void attn_flash_kernel(const __bf16* __restrict__ qw,
                                                         const __bf16* __restrict__ kw,
                                                         const __bf16* __restrict__ vtw,
                                                         const float* __restrict__ x,
                                                         float* __restrict__ y,
                                                         float* __restrict__ c_out) {
  int qt = blockIdx.x;      // 0..15  (128 q-rows per block)
  int h  = blockIdx.y;      // 0..15
  int b  = blockIdx.z;      // 0..1
  size_t hoff = (size_t)(b * NH + h) * S_LEN * HD;
  const __bf16* qh = qw + hoff;
  const __bf16* kh = kw + hoff;
  const __bf16* vth = vtw + hoff;     // [hd][s]
  __shared__ __align__(16) __bf16 Ks[64][72];
  __shared__ __align__(16) __bf16 Vt[80][72];        // rows 0..63: V^T; 64..79: ones
  __shared__ __align__(16) __bf16 Ps[4][2][16][72];  // [wave][grp][q][k]
  int tid = threadIdx.x;
  int wave = tid >> 6, lane = tid & 63;
  int g = lane >> 4, l15 = lane & 15;
  // ones rows for the row-sum MFMA trick
  {
    int rr = 64 + (tid >> 4);
    int cc = (tid & 15) * 4;
    bf16x4 one; one[0] = one[1] = one[2] = one[3] = (__bf16)1.0f;
    *(bf16x4*)&Vt[rr][cc] = one;
  }
  // Q fragments for both groups (q = qt*128 + grp*64 + wave*16 + l15)
  bf16x8 qf[2][2];
#pragma unroll
  for (int grp = 0; grp < 2; ++grp)
#pragma unroll
    for (int ks = 0; ks < 2; ++ks)
      qf[grp][ks] = *(const bf16x8*)&qh[(size_t)(qt * 128 + grp * 64 + wave * 16 + l15) * HD +
                                        ks * 32 + g * 8];
  float mrow[2] = {-1e30f, -1e30f};
  f32x4 ctx[2][4] = {};
  f32x4 lacc[2] = {};
  for (int kt = 0; kt < S_LEN / 64; ++kt) {
    __syncthreads();   // protect Ks/Vt restage vs prior iter reads (covers ones-init at kt=0)
#pragma unroll
    for (int i = 0; i < 2; ++i) {
      int idx = (i * 256 + tid) * 8;
      int r = idx >> 6, c = idx & 63;
      *(bf16x8*)&Ks[r][c] = *(const bf16x8*)&kh[(size_t)(kt * 64 + r) * HD + c];
      *(bf16x8*)&Vt[r][c] = *(const bf16x8*)&vth[(size_t)r * S_LEN + kt * 64 + c];
    }
    __syncthreads();
    // S^T = K * Q^T for both groups; kf shared
    f32x4 sacc[2][4] = {};
#pragma unroll
    for (int ks = 0; ks < 2; ++ks) {
      bf16x8 kf[4];
#pragma unroll
      for (int n = 0; n < 4; ++n)
        kf[n] = *(const bf16x8*)&Ks[n * 16 + l15][ks * 32 + g * 8];
#pragma unroll
      for (int grp = 0; grp < 2; ++grp)
#pragma unroll
        for (int n = 0; n < 4; ++n)
          sacc[grp][n] = __builtin_amdgcn_mfma_f32_16x16x32_bf16(kf[n], qf[grp][ks],
                                                                 sacc[grp][n], 0, 0, 0);
    }
    // softmax per group
#pragma unroll
    for (int grp = 0; grp < 2; ++grp) {
      float vmax = fmaxf(
          fmaxf(fmaxf(fmaxf(sacc[grp][0][0], sacc[grp][0][1]), fmaxf(sacc[grp][0][2], sacc[grp][0][3])),
                fmaxf(fmaxf(sacc[grp][1][0], sacc[grp][1][1]), fmaxf(sacc[grp][1][2], sacc[grp][1][3]))),
          fmaxf(fmaxf(fmaxf(sacc[grp][2][0], sacc[grp][2][1]), fmaxf(sacc[grp][2][2], sacc[grp][2][3])),
                fmaxf(fmaxf(sacc[grp][3][0], sacc[grp][3][1]), fmaxf(sacc[grp][3][2], sacc[grp][3][3]))));
      vmax = fmaxf(vmax, __shfl_xor(vmax, 16));
      vmax = fmaxf(vmax, __shfl_xor(vmax, 32));
      if (__any(vmax > mrow[grp])) {       // rescale only when some row's max grows
        float mnew = fmaxf(mrow[grp], vmax);
        float alpha = __builtin_amdgcn_exp2f(mrow[grp] - mnew);
        mrow[grp] = mnew;
        float av[4];
#pragma unroll
        for (int r = 0; r < 4; ++r) av[r] = __shfl(alpha, 4 * g + r);
#pragma unroll
        for (int n = 0; n < 4; ++n)
#pragma unroll
          for (int r = 0; r < 4; ++r) ctx[grp][n][r] *= av[r];
#pragma unroll
        for (int r = 0; r < 4; ++r) lacc[grp][r] *= av[r];
      }
      // P = exp2(S - m) -> wave-private LDS (b64 stores, contiguous in r)
#pragma unroll
      for (int n = 0; n < 4; ++n) {
        bf16x4 q4;
#pragma unroll
        for (int r = 0; r < 4; ++r)
          q4[r] = (__bf16)__builtin_amdgcn_exp2f(sacc[grp][n][r] - mrow[grp]);
        *(bf16x4*)&Ps[wave][grp][l15][n * 16 + 4 * g] = q4;
      }
    }
    // PV + row-sum; vf shared across groups
#pragma unroll
    for (int ks = 0; ks < 2; ++ks) {
      bf16x8 vf[4], vf1;
#pragma unroll
      for (int n = 0; n < 4; ++n)
        vf[n] = *(const bf16x8*)&Vt[n * 16 + l15][ks * 32 + g * 8];
      vf1 = *(const bf16x8*)&Vt[64 + l15][ks * 32 + g * 8];
#pragma unroll
      for (int grp = 0; grp < 2; ++grp) {
        bf16x8 pf = *(const bf16x8*)&Ps[wave][grp][l15][ks * 32 + g * 8];
#pragma unroll
        for (int n = 0; n < 4; ++n)
          ctx[grp][n] = __builtin_amdgcn_mfma_f32_16x16x32_bf16(pf, vf[n], ctx[grp][n], 0, 0, 0);
        lacc[grp] = __builtin_amdgcn_mfma_f32_16x16x32_bf16(pf, vf1, lacc[grp], 0, 0, 0);
      }
    }
  }
#pragma unroll
  for (int grp = 0; grp < 2; ++grp) {
    float il[4], cv[4];
#pragma unroll
    for (int r = 0; r < 4; ++r) {
      il[r] = 1.0f / lacc[grp][r];
      cv[r] = __shfl(mrow[grp], 4 * g + r) + __builtin_amdgcn_logf(lacc[grp][r]);  // m + log2(l)
    }
#pragma unroll
    for (int n = 0; n < 4; ++n)
#pragma unroll
      for (int r = 0; r < 4; ++r) {
        int qrow = qt * 128 + grp * 64 + wave * 16 + g * 4 + r;
        int dim = h * HD + n * 16 + l15;
        size_t yi = ((size_t)b * S_LEN + qrow) * DIM + dim;
        y[yi] = x[yi] + ctx[grp][n][r] * il[r];
      }
    if (l15 == 0) {
      size_t base = (size_t)(b * NH + h) * S_LEN + qt * 128 + grp * 64 + wave * 16;
#pragma unroll
      for (int r = 0; r < 4; ++r) c_out[base + 4 * g + r] = cv[r];
    }
  }
}

// ---------------- head-mean of attention probabilities (no LDS, no barriers) ----------------
// P[h][q][k] = exp2(S - c[h][q]) with c = m + log2(l); Q pre-scaled (exp2 domain).
// K fragments read directly from global: 16 rows x 16B per instr = 16 full cachelines,
// L1/L2-resident (8KB tile), so no staging needed.
__global__ __launch_bounds__(256) void attn_mean_kernel(const __bf16* __restrict__ qw,
                                                        const __bf16* __restrict__ kw,
                                                        const float* __restrict__ c_in,
                                                        float* __restrict__ out_mean) {
  int kt = blockIdx.x, qt = blockIdx.y, b = blockIdx.z;
  int tid = threadIdx.x;
  int wave = tid >> 6, lane = tid & 63;
  int g = lane >> 4, l15 = lane & 15;
  int qrow = qt * 64 + wave * 16 + l15;
  const __bf16* qp = qw + (size_t)b * NH * S_LEN * HD + (size_t)qrow * HD;
  const __bf16* kp = kw + (size_t)b * NH * S_LEN * HD;
  const float*  cp = c_in + (size_t)b * NH * S_LEN + qrow;
  f32x4 macc[4] = {};
  for (int h = 0; h < NH; ++h) {
    bf16x8 qf[2];
#pragma unroll
    for (int ks = 0; ks < 2; ++ks)
      qf[ks] = *(const bf16x8*)&qp[(size_t)h * S_LEN * HD + ks * 32 + g * 8];
    f32x4 sacc[4] = {};
#pragma unroll
    for (int ks = 0; ks < 2; ++ks) {
      bf16x8 kf[4];
#pragma unroll
      for (int n = 0; n < 4; ++n)
        kf[n] = *(const bf16x8*)&kp[(size_t)h * S_LEN * HD +
                                    (size_t)(kt * 64 + n * 16 + l15) * HD + ks * 32 + g * 8];
#pragma unroll
      for (int n = 0; n < 4; ++n)
        sacc[n] = __builtin_amdgcn_mfma_f32_16x16x32_bf16(kf[n], qf[ks], sacc[n], 0, 0, 0);
    }
    float c = cp[(size_t)h * S_LEN];
#pragma unroll
    for (int n = 0; n < 4; ++n)
#pragma unroll
      for (int r = 0; r < 4; ++r)
        macc[n][r] += __builtin_amdgcn_exp2f(sacc[n][r] - c);
  }
  const float invh = 1.0f / (float)NH;
#pragma unroll
  for (int n = 0; n < 4; ++n) {
    f32x4 o;
#pragma unroll
    for (int r = 0; r < 4; ++r) o[r] = macc[n][r] * invh;
    // k = kt*64 + n*16 + 4g + r  contiguous in r -> float4 store
    *(f32x4*)&out_mean[((size_t)b * S_LEN + qrow) * S_LEN + kt * 64 + n * 16 + 4 * g] = o;
  }
}

// ---------------- LayerNorm over D=1024 ----------------
__global__ __launch_bounds__(256) void ln_kernel(const float* __restrict__ y,
                                                 const float* __restrict__ gamma,
                                                 const float* __restrict__ beta,
                                                 float* __restrict__ out) {
  int row = blockIdx.x;
  const float* yr = y + (size_t)row * DIM;
  int tid = threadIdx.x;
  float4 v = *(const float4*)&yr[tid * 4];
  float s = v.x + v.y + v.z + v.w;
  float sq = v.x * v.x + v.y * v.y + v.z * v.z + v.w * v.w;
#pragma unroll
  for (int off = 1; off < 64; off <<= 1) {
    s += __shfl_xor(s, off);
    sq += __shfl_xor(sq, off);
  }
  __shared__ float red[8];
  int wave = tid >> 6, lane = tid & 63;
  if (lane == 0) { red[wave] = s; red[4 + wave] = sq; }
  __syncthreads();
  s = red[0] + red[1] + red[2] + red[3];
  sq = red[4] + red[5] + red[6] + red[7];
  float mu = s * (1.0f / DIM);
  float var = sq * (1.0f / DIM) - mu * mu;
  float rstd = rsqrtf(var + 1e-5f);
  float* orow = out + (size_t)row * DIM;
  float4 gv = *(const float4*)&gamma[tid * 4];
  float4 bv = *(const float4*)&beta[tid * 4];
  float4 ov;
  ov.x = (v.x - mu) * rstd * gv.x + bv.x;
  ov.y = (v.y - mu) * rstd * gv.y + bv.y;
  ov.z = (v.z - mu) * rstd * gv.z + bv.z;
  ov.w = (v.w - mu) * rstd * gv.w + bv.w;
  *(float4*)&orow[tid * 4] = ov;
}

extern "C" void kernel_launch(void* const* d_in, const int* in_sizes, int n_in,
                              void* d_out, int out_size, void* d_ws, size_t ws_size,
                              hipStream_t stream) {
  const float* x  = (const float*)d_in[0];
  const float* Wq = (const float*)d_in[1];
  const float* bq = (const float*)d_in[2];
  const float* Wk = (const float*)d_in[3];
  const float* bk = (const float*)d_in[4];
  const float* Wv = (const float*)d_in[5];
  const float* bv = (const float*)d_in[6];
  const float* gamma = (const float*)d_in[7];
  const float* beta  = (const float*)d_in[8];
  float* out = (float*)d_out;                 // [0,4194304): LN out ; [4194304,...): attn mean

  char* ws = (char*)d_ws;
  __bf16* xb   = (__bf16*)ws;                       // 8,388,608 B
  __bf16* WT   = (__bf16*)(ws + 8388608);           // 6,291,456 B
  __bf16* qkv  = (__bf16*)(ws + 14680064);          // 25,165,824 B (Q pre-scaled; V is [b,h,hd,s])
  float*  y    = (float*)(ws + 39845888);           // 16,777,216 B
  float*  c_ws = (float*)(ws + 56623104);           // 262,144 B (m + log2(l) per b,h,q)

  cast_x_kernel<<<2048, 256, 0, stream>>>(x, xb);
  transW_kernel<<<dim3(16, 16, 3), 256, 0, stream>>>(Wq, Wk, Wv, WT);
  qkv_gemm_kernel<<<dim3(8, 32, 3), 256, 0, stream>>>(xb, WT, bq, bk, bv, qkv);
  attn_flash_kernel<<<dim3(16, 16, 2), 256, 0, stream>>>(qkv, qkv + 4194304, qkv + 8388608,
                                                         x, y, c_ws);
  attn_mean_kernel<<<dim3(32, 32, 2), 256, 0, stream>>>(qkv, qkv + 4194304, c_ws,
                                                        out + 4194304);
  ln_kernel<<<4096, 256, 0, stream>>>(y, gamma, beta, out);
}

// Round 6
// 193.033 us; speedup vs baseline: 1.5062x; 1.5062x over previous
//
#include <hip/hip_runtime.h>

#define S_LEN 2048
#define DIM   1024
#define NH    16
#define HD    64

typedef __bf16 bf16x8 __attribute__((ext_vector_type(8)));
typedef __bf16 bf16x4 __attribute__((ext_vector_type(4)));
typedef float  f32x4  __attribute__((ext_vector_type(4)));

// softmax scale 1/8 with log2(e) folded in -> use v_exp_f32 (exp2) directly
#define SCALE_Q (0.125f * 1.44269504088896f)

#define GLOAD_LDS16(g, l) __builtin_amdgcn_global_load_lds( \
    (const __attribute__((address_space(1))) void*)(g),     \
    (__attribute__((address_space(3))) void*)(l), 16, 0, 0)

// ---------------- cast x (fp32 -> bf16), 8 elems/thread ----------------
__global__ __launch_bounds__(256) void cast_x_kernel(const float* __restrict__ x,
                                                     __bf16* __restrict__ xb) {
  int i = blockIdx.x * 256 + threadIdx.x;   // 0..524287
  const float4 a = ((const float4*)x)[i * 2];
  const float4 b = ((const float4*)x)[i * 2 + 1];
  bf16x8 o;
  o[0] = (__bf16)a.x; o[1] = (__bf16)a.y; o[2] = (__bf16)a.z; o[3] = (__bf16)a.w;
  o[4] = (__bf16)b.x; o[5] = (__bf16)b.y; o[6] = (__bf16)b.z; o[7] = (__bf16)b.w;
  ((bf16x8*)xb)[i] = o;
}

// ---------------- W [k][n] fp32 -> WT [n][k] bf16, 64x64 LDS tiles ----------------
__global__ __launch_bounds__(256) void transW_kernel(const float* __restrict__ Wq,
                                                     const float* __restrict__ Wk,
                                                     const float* __restrict__ Wv,
                                                     __bf16* __restrict__ WT) {
  int which = blockIdx.z;
  const float* W = (which == 0) ? Wq : ((which == 1) ? Wk : Wv);
  __bf16* o = WT + (size_t)which * DIM * DIM;
  __shared__ __bf16 t[64][65];
  int k0 = blockIdx.y * 64, n0 = blockIdx.x * 64;
  int tid = threadIdx.x;
  int c4 = (tid & 15) * 4, rb = tid >> 4;   // rb 0..15
#pragma unroll
  for (int p = 0; p < 4; ++p) {
    int r = p * 16 + rb;
    float4 a = *(const float4*)&W[(size_t)(k0 + r) * DIM + n0 + c4];
    t[r][c4 + 0] = (__bf16)a.x; t[r][c4 + 1] = (__bf16)a.y;
    t[r][c4 + 2] = (__bf16)a.z; t[r][c4 + 3] = (__bf16)a.w;
  }
  __syncthreads();
#pragma unroll
  for (int p = 0; p < 4; ++p) {
    int n = p * 16 + rb;                     // output row (n dim)
    bf16x4 v;
    v[0] = t[c4 + 0][n]; v[1] = t[c4 + 1][n];
    v[2] = t[c4 + 2][n]; v[3] = t[c4 + 3][n];
    *(bf16x4*)&o[(size_t)(n0 + n) * DIM + k0 + c4] = v;
  }
}

// ---------------- QKV GEMM, m97 structure: global_load_lds staging, linear LDS ----------------
// which==0 (Q): output pre-scaled by SCALE_Q (softmax+log2e folded).
// which==1 (K): [b,h,s,hd].  which==2 (V): TRANSPOSED [b,h,hd,s] via LDS tile transpose.
__global__ __launch_bounds__(256) void qkv_gemm_kernel(const __bf16* __restrict__ xb,
                                                       const __bf16* __restrict__ WT,
                                                       const float* __restrict__ bq,
                                                       const float* __restrict__ bk,
                                                       const float* __restrict__ bv,
                                                       __bf16* __restrict__ qkv) {
  int which = blockIdx.z;
  const __bf16* Wt = WT + (size_t)which * DIM * DIM;
  const float* bias = (which == 0) ? bq : ((which == 1) ? bk : bv);
  __bf16* outp = qkv + (size_t)which * 2 * NH * S_LEN * HD;
  int m0 = blockIdx.y * 128;
  int n0 = blockIdx.x * 128;
  __shared__ __align__(16) char smem[36864];
  __bf16 (*As)[64] = (__bf16(*)[64])smem;            // 16384 B, linear (for global_load_lds)
  __bf16 (*Bs)[64] = (__bf16(*)[64])(smem + 16384);  // 16384 B
  __bf16 (*Ct)[136] = (__bf16(*)[136])smem;          // aliased; used only after final barrier
  int tid = threadIdx.x;
  int wave = tid >> 6, lane = tid & 63;
  int g = lane >> 4, l15 = lane & 15;
  int wm = (wave >> 1) * 64, wn = (wave & 1) * 64;
  // staging: wave w owns rows w*32..w*32+31; each GLL writes 1KB = 8 rows x 128B
  int lr = lane >> 3;            // 0..7 row within 8-row chunk
  int lc = (lane & 7) * 8;       // elem col (16B per lane)
  const __bf16* ga = &xb[(size_t)(m0 + wave * 32 + lr) * DIM + lc];
  const __bf16* gb = &Wt[(size_t)(n0 + wave * 32 + lr) * DIM + lc];
  f32x4 acc[4][4] = {};
  for (int k0 = 0; k0 < DIM; k0 += 64) {
#pragma unroll
    for (int c = 0; c < 4; ++c) {
      GLOAD_LDS16(ga + k0 + (size_t)(c * 8) * DIM, &As[wave * 32 + c * 8][0]);
      GLOAD_LDS16(gb + k0 + (size_t)(c * 8) * DIM, &Bs[wave * 32 + c * 8][0]);
    }
    __syncthreads();
#pragma unroll
    for (int ks = 0; ks < 2; ++ks) {
      bf16x8 af[4], bfr[4];
#pragma unroll
      for (int s = 0; s < 4; ++s) {
        af[s]  = *(const bf16x8*)&As[wm + s * 16 + l15][ks * 32 + g * 8];
        bfr[s] = *(const bf16x8*)&Bs[wn + s * 16 + l15][ks * 32 + g * 8];
      }
#pragma unroll
      for (int i = 0; i < 4; ++i)
#pragma unroll
        for (int j = 0; j < 4; ++j)
          acc[i][j] = __builtin_amdgcn_mfma_f32_16x16x32_bf16(af[i], bfr[j], acc[i][j], 0, 0, 0);
    }
    __syncthreads();
  }
  if (which != 2) {
    float scale = (which == 0) ? SCALE_Q : 1.0f;
#pragma unroll
    for (int i = 0; i < 4; ++i)
#pragma unroll
      for (int j = 0; j < 4; ++j) {
        int n = n0 + wn + j * 16 + l15;
        float bval = bias[n];
#pragma unroll
        for (int r = 0; r < 4; ++r) {
          int m = m0 + wm + i * 16 + g * 4 + r;
          float val = (acc[i][j][r] + bval) * scale;
          int bb = m >> 11, ss = m & 2047;
          int hh = n >> 6, hd = n & 63;
          outp[(((size_t)bb * NH + hh) * S_LEN + ss) * HD + hd] = (__bf16)val;
        }
      }
  } else {
    // V: transpose tile in LDS (writes are bf16x4 along contiguous m), store [b,h,hd,s]
#pragma unroll
    for (int i = 0; i < 4; ++i)
#pragma unroll
      for (int j = 0; j < 4; ++j) {
        int nl = wn + j * 16 + l15;
        float bval = bias[n0 + nl];
        bf16x4 t;
#pragma unroll
        for (int r = 0; r < 4; ++r) t[r] = (__bf16)(acc[i][j][r] + bval);
        *(bf16x4*)&Ct[nl][wm + i * 16 + g * 4] = t;
      }
    __syncthreads();
#pragma unroll
    for (int it = 0; it < 8; ++it) {
      int idx = (it * 256 + tid) * 8;
      int row = idx >> 7, col = idx & 127;       // row = n_local, col = m_local
      int n = n0 + row, hh = n >> 6, hd = n & 63;
      int m = m0 + col, bb = m >> 11, ss = m & 2047;
      *(bf16x8*)&outp[(((size_t)bb * NH + hh) * HD + hd) * S_LEN + ss] =
          *(const bf16x8*)&Ct[row][col];
    }
  }
}

// ---------------- flash attention + residual, QBLK=128 ----------------
// Q pre-scaled by SCALE_Q (exp2 domain); V pre-transposed [b,h,hd,s].
// Each wave owns TWO 16-q groups so the kf/vf LDS reads amortize over 2x MFMA.
__global__ __launch_bounds__(256) void attn_flash_kernel(const __bf16* __restrict__ qw,
                                                         const __bf16* __restrict__ kw,
                                                         const __bf16* __restrict__ vtw,
                                                         const float* __restrict__ x,
                                                         float* __restrict__ y,
                                                         float* __restrict__ c_out) {
  int qt = blockIdx.x;      // 0..15  (128 q-rows per block)
  int h  = blockIdx.y;      // 0..15
  int b  = blockIdx.z;      // 0..1
  size_t hoff = (size_t)(b * NH + h) * S_LEN * HD;
  const __bf16* qh = qw + hoff;
  const __bf16* kh = kw + hoff;
  const __bf16* vth = vtw + hoff;     // [hd][s]
  __shared__ __align__(16) __bf16 Ks[64][72];
  __shared__ __align__(16) __bf16 Vt[80][72];        // rows 0..63: V^T; 64..79: ones
  __shared__ __align__(16) __bf16 Ps[4][2][16][72];  // [wave][grp][q][k]
  int tid = threadIdx.x;
  int wave = tid >> 6, lane = tid & 63;
  int g = lane >> 4, l15 = lane & 15;
  // ones rows for the row-sum MFMA trick
  {
    int rr = 64 + (tid >> 4);
    int cc = (tid & 15) * 4;
    bf16x4 one; one[0] = one[1] = one[2] = one[3] = (__bf16)1.0f;
    *(bf16x4*)&Vt[rr][cc] = one;
  }
  // Q fragments for both groups (q = qt*128 + grp*64 + wave*16 + l15)
  bf16x8 qf[2][2];
#pragma unroll
  for (int grp = 0; grp < 2; ++grp)
#pragma unroll
    for (int ks = 0; ks < 2; ++ks)
      qf[grp][ks] = *(const bf16x8*)&qh[(size_t)(qt * 128 + grp * 64 + wave * 16 + l15) * HD +
                                        ks * 32 + g * 8];
  float mrow[2] = {-1e30f, -1e30f};
  f32x4 ctx[2][4] = {};
  f32x4 lacc[2] = {};
  for (int kt = 0; kt < S_LEN / 64; ++kt) {
    __syncthreads();   // protect Ks/Vt restage vs prior iter reads (covers ones-init at kt=0)
#pragma unroll
    for (int i = 0; i < 2; ++i) {
      int idx = (i * 256 + tid) * 8;
      int r = idx >> 6, c = idx & 63;
      *(bf16x8*)&Ks[r][c] = *(const bf16x8*)&kh[(size_t)(kt * 64 + r) * HD + c];
      *(bf16x8*)&Vt[r][c] = *(const bf16x8*)&vth[(size_t)r * S_LEN + kt * 64 + c];
    }
    __syncthreads();
    // S^T = K * Q^T for both groups; kf shared
    f32x4 sacc[2][4] = {};
#pragma unroll
    for (int ks = 0; ks < 2; ++ks) {
      bf16x8 kf[4];
#pragma unroll
      for (int n = 0; n < 4; ++n)
        kf[n] = *(const bf16x8*)&Ks[n * 16 + l15][ks * 32 + g * 8];
#pragma unroll
      for (int grp = 0; grp < 2; ++grp)
#pragma unroll
        for (int n = 0; n < 4; ++n)
          sacc[grp][n] = __builtin_amdgcn_mfma_f32_16x16x32_bf16(kf[n], qf[grp][ks],
                                                                 sacc[grp][n], 0, 0, 0);
    }
    // softmax per group
#pragma unroll
    for (int grp = 0; grp < 2; ++grp) {
      float vmax = fmaxf(
          fmaxf(fmaxf(fmaxf(sacc[grp][0][0], sacc[grp][0][1]), fmaxf(sacc[grp][0][2], sacc[grp][0][3])),
                fmaxf(fmaxf(sacc[grp][1][0], sacc[grp][1][1]), fmaxf(sacc[grp][1][2], sacc[grp][1][3]))),
          fmaxf(fmaxf(fmaxf(sacc[grp][2][0], sacc[grp][2][1]), fmaxf(sacc[grp][2][2], sacc[grp][2][3])),
                fmaxf(fmaxf(sacc[grp][3][0], sacc[grp][3][1]), fmaxf(sacc[grp][3][2], sacc[grp][3][3]))));
      vmax = fmaxf(vmax, __shfl_xor(vmax, 16));
      vmax = fmaxf(vmax, __shfl_xor(vmax, 32));
      if (__any(vmax > mrow[grp])) {       // rescale only when some row's max grows
        float mnew = fmaxf(mrow[grp], vmax);
        float alpha = __builtin_amdgcn_exp2f(mrow[grp] - mnew);
        mrow[grp] = mnew;
        float av[4];
#pragma unroll
        for (int r = 0; r < 4; ++r) av[r] = __shfl(alpha, 4 * g + r);
#pragma unroll
        for (int n = 0; n < 4; ++n)
#pragma unroll
          for (int r = 0; r < 4; ++r) ctx[grp][n][r] *= av[r];
#pragma unroll
        for (int r = 0; r < 4; ++r) lacc[grp][r] *= av[r];
      }
      // P = exp2(S - m) -> wave-private LDS (b64 stores, contiguous in r)
#pragma unroll
      for (int n = 0; n < 4; ++n) {
        bf16x4 q4;
#pragma unroll
        for (int r = 0; r < 4; ++r)
          q4[r] = (__bf16)__builtin_amdgcn_exp2f(sacc[grp][n][r] - mrow[grp]);
        *(bf16x4*)&Ps[wave][grp][l15][n * 16 + 4 * g] = q4;
      }
    }
    // PV + row-sum; vf shared across groups
#pragma unroll
    for (int ks = 0; ks < 2; ++ks) {
      bf16x8 vf[4], vf1;
#pragma unroll
      for (int n = 0; n < 4; ++n)
        vf[n] = *(const bf16x8*)&Vt[n * 16 + l15][ks * 32 + g * 8];
      vf1 = *(const bf16x8*)&Vt[64 + l15][ks * 32 + g * 8];
#pragma unroll
      for (int grp = 0; grp < 2; ++grp) {
        bf16x8 pf = *(const bf16x8*)&Ps[wave][grp][l15][ks * 32 + g * 8];
#pragma unroll
        for (int n = 0; n < 4; ++n)
          ctx[grp][n] = __builtin_amdgcn_mfma_f32_16x16x32_bf16(pf, vf[n], ctx[grp][n], 0, 0, 0);
        lacc[grp] = __builtin_amdgcn_mfma_f32_16x16x32_bf16(pf, vf1, lacc[grp], 0, 0, 0);
      }
    }
  }
#pragma unroll
  for (int grp = 0; grp < 2; ++grp) {
    float il[4], cv[4];
#pragma unroll
    for (int r = 0; r < 4; ++r) {
      il[r] = 1.0f / lacc[grp][r];
      cv[r] = __shfl(mrow[grp], 4 * g + r) + __builtin_amdgcn_logf(lacc[grp][r]);  // m + log2(l)
    }
#pragma unroll
    for (int n = 0; n < 4; ++n)
#pragma unroll
      for (int r = 0; r < 4; ++r) {
        int qrow = qt * 128 + grp * 64 + wave * 16 + g * 4 + r;
        int dim = h * HD + n * 16 + l15;
        size_t yi = ((size_t)b * S_LEN + qrow) * DIM + dim;
        y[yi] = x[yi] + ctx[grp][n][r] * il[r];
      }
    if (l15 == 0) {
      size_t base = (size_t)(b * NH + h) * S_LEN + qt * 128 + grp * 64 + wave * 16;
#pragma unroll
      for (int r = 0; r < 4; ++r) c_out[base + 4 * g + r] = cv[r];
    }
  }
}

// ---------------- head-mean of attention probabilities, QBLK=128 ----------------
// P[h][q][k] = exp2(S - c[h][q]) with c = m + log2(l); Q pre-scaled (exp2 domain).
// LDS-staged K per head (latency amortization); kf reads shared across 2 q-groups.
__global__ __launch_bounds__(256) void attn_mean_kernel(const __bf16* __restrict__ qw,
                                                        const __bf16* __restrict__ kw,
                                                        const float* __restrict__ c_in,
                                                        float* __restrict__ out_mean) {
  int kt = blockIdx.x, qt = blockIdx.y, b = blockIdx.z;
  __shared__ __align__(16) __bf16 Ks[64][72];
  int tid = threadIdx.x;
  int wave = tid >> 6, lane = tid & 63;
  int g = lane >> 4, l15 = lane & 15;
  const __bf16* qp = qw + (size_t)b * NH * S_LEN * HD;
  const __bf16* kp = kw + (size_t)b * NH * S_LEN * HD;
  f32x4 macc[2][4] = {};
  for (int h = 0; h < NH; ++h) {
    size_t hb = (size_t)h * S_LEN * HD;
    __syncthreads();
#pragma unroll
    for (int i = 0; i < 2; ++i) {
      int idx = (i * 256 + tid) * 8;
      int r = idx >> 6, c = idx & 63;
      *(bf16x8*)&Ks[r][c] = *(const bf16x8*)&kp[hb + (size_t)(kt * 64 + r) * HD + c];
    }
    __syncthreads();
    f32x4 sacc[2][4] = {};
#pragma unroll
    for (int ks = 0; ks < 2; ++ks) {
      bf16x8 kf[4];
#pragma unroll
      for (int n = 0; n < 4; ++n)
        kf[n] = *(const bf16x8*)&Ks[n * 16 + l15][ks * 32 + g * 8];
#pragma unroll
      for (int grp = 0; grp < 2; ++grp) {
        bf16x8 qf = *(const bf16x8*)&qp[hb + (size_t)(qt * 128 + grp * 64 + wave * 16 + l15) * HD +
                                        ks * 32 + g * 8];
#pragma unroll
        for (int n = 0; n < 4; ++n)
          sacc[grp][n] = __builtin_amdgcn_mfma_f32_16x16x32_bf16(kf[n], qf, sacc[grp][n], 0, 0, 0);
      }
    }
#pragma unroll
    for (int grp = 0; grp < 2; ++grp) {
      float c = c_in[(size_t)(b * NH + h) * S_LEN + qt * 128 + grp * 64 + wave * 16 + l15];
#pragma unroll
      for (int n = 0; n < 4; ++n)
#pragma unroll
        for (int r = 0; r < 4; ++r)
          macc[grp][n][r] += __builtin_amdgcn_exp2f(sacc[grp][n][r] - c);
    }
  }
  const float invh = 1.0f / (float)NH;
#pragma unroll
  for (int grp = 0; grp < 2; ++grp) {
    int qrow = qt * 128 + grp * 64 + wave * 16 + l15;
#pragma unroll
    for (int n = 0; n < 4; ++n) {
      f32x4 o;
#pragma unroll
      for (int r = 0; r < 4; ++r) o[r] = macc[grp][n][r] * invh;
      // k = kt*64 + n*16 + 4g + r  contiguous in r -> float4 store
      *(f32x4*)&out_mean[((size_t)b * S_LEN + qrow) * S_LEN + kt * 64 + n * 16 + 4 * g] = o;
    }
  }
}

// ---------------- LayerNorm over D=1024 ----------------
__global__ __launch_bounds__(256) void ln_kernel(const float* __restrict__ y,
                                                 const float* __restrict__ gamma,
                                                 const float* __restrict__ beta,
                                                 float* __restrict__ out) {
  int row = blockIdx.x;
  const float* yr = y + (size_t)row * DIM;
  int tid = threadIdx.x;
  float4 v = *(const float4*)&yr[tid * 4];
  float s = v.x + v.y + v.z + v.w;
  float sq = v.x * v.x + v.y * v.y + v.z * v.z + v.w * v.w;
#pragma unroll
  for (int off = 1; off < 64; off <<= 1) {
    s += __shfl_xor(s, off);
    sq += __shfl_xor(sq, off);
  }
  __shared__ float red[8];
  int wave = tid >> 6, lane = tid & 63;
  if (lane == 0) { red[wave] = s; red[4 + wave] = sq; }
  __syncthreads();
  s = red[0] + red[1] + red[2] + red[3];
  sq = red[4] + red[5] + red[6] + red[7];
  float mu = s * (1.0f / DIM);
  float var = sq * (1.0f / DIM) - mu * mu;
  float rstd = rsqrtf(var + 1e-5f);
  float* orow = out + (size_t)row * DIM;
  float4 gv = *(const float4*)&gamma[tid * 4];
  float4 bv = *(const float4*)&beta[tid * 4];
  float4 ov;
  ov.x = (v.x - mu) * rstd * gv.x + bv.x;
  ov.y = (v.y - mu) * rstd * gv.y + bv.y;
  ov.z = (v.z - mu) * rstd * gv.z + bv.z;
  ov.w = (v.w - mu) * rstd * gv.w + bv.w;
  *(float4*)&orow[tid * 4] = ov;
}

extern "C" void kernel_launch(void* const* d_in, const int* in_sizes, int n_in,
                              void* d_out, int out_size, void* d_ws, size_t ws_size,
                              hipStream_t stream) {
  const float* x  = (const float*)d_in[0];
  const float* Wq = (const float*)d_in[1];
  const float* bq = (const float*)d_in[2];
  const float* Wk = (const float*)d_in[3];
  const float* bk = (const float*)d_in[4];
  const float* Wv = (const float*)d_in[5];
  const float* bv = (const float*)d_in[6];
  const float* gamma = (const float*)d_in[7];
  const float* beta  = (const float*)d_in[8];
  float* out = (float*)d_out;                 // [0,4194304): LN out ; [4194304,...): attn mean

  char* ws = (char*)d_ws;
  __bf16* xb   = (__bf16*)ws;                       // 8,388,608 B
  __bf16* WT   = (__bf16*)(ws + 8388608);           // 6,291,456 B
  __bf16* qkv  = (__bf16*)(ws + 14680064);          // 25,165,824 B (Q pre-scaled; V is [b,h,hd,s])
  float*  y    = (float*)(ws + 39845888);           // 16,777,216 B
  float*  c_ws = (float*)(ws + 56623104);           // 262,144 B (m + log2(l) per b,h,q)

  cast_x_kernel<<<2048, 256, 0, stream>>>(x, xb);
  transW_kernel<<<dim3(16, 16, 3), 256, 0, stream>>>(Wq, Wk, Wv, WT);
  qkv_gemm_kernel<<<dim3(8, 32, 3), 256, 0, stream>>>(xb, WT, bq, bk, bv, qkv);
  attn_flash_kernel<<<dim3(16, 16, 2), 256, 0, stream>>>(qkv, qkv + 4194304, qkv + 8388608,
                                                         x, y, c_ws);
  attn_mean_kernel<<<dim3(32, 16, 2), 256, 0, stream>>>(qkv, qkv + 4194304, c_ws,
                                                        out + 4194304);
  ln_kernel<<<4096, 256, 0, stream>>>(y, gamma, beta, out);
}